// Round 1
// baseline (135.697 us; speedup 1.0000x reference)
//
#include <hip/hip_runtime.h>
#include <hip/hip_bf16.h>
#include <stdint.h>

typedef float f32x4 __attribute__((ext_vector_type(4)));
typedef short s16x8 __attribute__((ext_vector_type(8)));
typedef int   i32x4 __attribute__((ext_vector_type(4)));

#define NNODES 4096
#define INC    256
#define OUTF   256
#define NEG    0.2f

__device__ __forceinline__ unsigned short f2bf(float f) {
  unsigned u = __float_as_uint(f);
  u += 0x7FFFu + ((u >> 16) & 1u);          // RNE
  return (unsigned short)(u >> 16);
}
__device__ __forceinline__ unsigned encf(float x) {
  unsigned u = __float_as_uint(x);
  return (u & 0x80000000u) ? ~u : (u | 0x80000000u);
}
__device__ __forceinline__ float decf(unsigned e) {
  unsigned u = (e & 0x80000000u) ? (e ^ 0x80000000u) : ~e;
  return __uint_as_float(u);
}

// ---------------------------------------------------------------------------
// Kernel A: h = x @ W (f32 accurate), write hT (bf16, [c_global][n]),
// el/er logits (f32), and atomicMax of global er max per head.
// Grid: (4 heads/c-blocks, 64 n-blocks), 256 threads. Tile 64x64, BK=32.
// ---------------------------------------------------------------------------
__global__ __launch_bounds__(256) void k_feat(
    const float* __restrict__ x, const float* __restrict__ W,
    const float* __restrict__ attl, const float* __restrict__ attr,
    unsigned short* __restrict__ hT, float* __restrict__ el_t,
    float* __restrict__ er_t, unsigned* __restrict__ M_enc)
{
  __shared__ float sm[4352];
  float* xs  = sm;          // [32][68]  x^T chunk (k-major)
  float* wsl = sm + 2176;   // [32][68]  W chunk (k-major)
  const int tid = threadIdx.x;
  const int hb = blockIdx.x, nb = blockIdx.y;
  const int n0 = nb * 64, c0 = hb * 64;
  const int ty = tid >> 4, tx = tid & 15;

  float acc[4][4];
#pragma unroll
  for (int r = 0; r < 4; ++r)
#pragma unroll
    for (int j = 0; j < 4; ++j) acc[r][j] = 0.f;

  const int sn = tid >> 2, sko = (tid & 3) * 8;
  const int wk = tid >> 3, wco = (tid & 7) * 8;

  for (int kc = 0; kc < INC; kc += 32) {
    __syncthreads();
    {
      const float* xp = x + (size_t)(n0 + sn) * INC + kc + sko;
      float4 a = *(const float4*)xp;
      float4 b = *(const float4*)(xp + 4);
      xs[(sko + 0) * 68 + sn] = a.x; xs[(sko + 1) * 68 + sn] = a.y;
      xs[(sko + 2) * 68 + sn] = a.z; xs[(sko + 3) * 68 + sn] = a.w;
      xs[(sko + 4) * 68 + sn] = b.x; xs[(sko + 5) * 68 + sn] = b.y;
      xs[(sko + 6) * 68 + sn] = b.z; xs[(sko + 7) * 68 + sn] = b.w;
      const float* wp = W + (size_t)(kc + wk) * OUTF + c0 + wco;
      *(float4*)(wsl + wk * 68 + wco)     = *(const float4*)wp;
      *(float4*)(wsl + wk * 68 + wco + 4) = *(const float4*)(wp + 4);
    }
    __syncthreads();
#pragma unroll
    for (int k = 0; k < 32; ++k) {
      float4 a = *(const float4*)(xs + k * 68 + ty * 4);
      float4 b = *(const float4*)(wsl + k * 68 + tx * 4);
      acc[0][0] = fmaf(a.x, b.x, acc[0][0]); acc[0][1] = fmaf(a.x, b.y, acc[0][1]);
      acc[0][2] = fmaf(a.x, b.z, acc[0][2]); acc[0][3] = fmaf(a.x, b.w, acc[0][3]);
      acc[1][0] = fmaf(a.y, b.x, acc[1][0]); acc[1][1] = fmaf(a.y, b.y, acc[1][1]);
      acc[1][2] = fmaf(a.y, b.z, acc[1][2]); acc[1][3] = fmaf(a.y, b.w, acc[1][3]);
      acc[2][0] = fmaf(a.z, b.x, acc[2][0]); acc[2][1] = fmaf(a.z, b.y, acc[2][1]);
      acc[2][2] = fmaf(a.z, b.z, acc[2][2]); acc[2][3] = fmaf(a.z, b.w, acc[2][3]);
      acc[3][0] = fmaf(a.w, b.x, acc[3][0]); acc[3][1] = fmaf(a.w, b.y, acc[3][1]);
      acc[3][2] = fmaf(a.w, b.z, acc[3][2]); acc[3][3] = fmaf(a.w, b.w, acc[3][3]);
    }
  }

  // el/er: this block covers ALL 64 channels of head hb -> complete logits.
  float4 al = *(const float4*)(attl + c0 + tx * 4);
  float4 ar = *(const float4*)(attr + c0 + tx * 4);
  float pl[4], pr[4];
#pragma unroll
  for (int r = 0; r < 4; ++r) {
    pl[r] = acc[r][0] * al.x + acc[r][1] * al.y + acc[r][2] * al.z + acc[r][3] * al.w;
    pr[r] = acc[r][0] * ar.x + acc[r][1] * ar.y + acc[r][2] * ar.z + acc[r][3] * ar.w;
  }
#pragma unroll
  for (int m = 1; m < 16; m <<= 1) {
#pragma unroll
    for (int r = 0; r < 4; ++r) {
      pl[r] += __shfl_xor(pl[r], m, 64);
      pr[r] += __shfl_xor(pr[r], m, 64);
    }
  }
  if (tx == 0) {
#pragma unroll
    for (int r = 0; r < 4; ++r) {
      el_t[hb * NNODES + n0 + ty * 4 + r] = pl[r];
      er_t[hb * NNODES + n0 + ty * 4 + r] = pr[r];
    }
  }
  float mx = fmaxf(fmaxf(pr[0], pr[1]), fmaxf(pr[2], pr[3]));
  mx = fmaxf(mx, __shfl_xor(mx, 16, 64));
  mx = fmaxf(mx, __shfl_xor(mx, 32, 64));
  if ((tid & 63) == 0) atomicMax(M_enc + hb, encf(mx));

  // transpose tile via LDS and store hT (bf16) with 16B stores
  __syncthreads();
#pragma unroll
  for (int r = 0; r < 4; ++r)
#pragma unroll
    for (int j = 0; j < 4; ++j)
      sm[(tx * 4 + j) * 68 + ty * 4 + r] = acc[r][j];
  __syncthreads();
  {
    const int c = tid >> 2, ns = (tid & 3) * 16;
    unsigned v[8];
#pragma unroll
    for (int i = 0; i < 8; ++i) {
      unsigned lo = f2bf(sm[c * 68 + ns + 2 * i]);
      unsigned hi = f2bf(sm[c * 68 + ns + 2 * i + 1]);
      v[i] = lo | (hi << 16);
    }
    unsigned short* dst = hT + (size_t)(c0 + c) * NNODES + n0 + ns;
    *(uint4*)(dst)     = make_uint4(v[0], v[1], v[2], v[3]);
    *(uint4*)(dst + 8) = make_uint4(v[4], v[5], v[6], v[7]);
  }
}

// ---------------------------------------------------------------------------
// Kernel B: fused masked-softmax + PV via MFMA. One wave = 16 i-rows x 1 head.
// Block = 4 waves = 64 i-rows, same head (shared B-frag/adj locality via L1).
// Grid: (64 i-superchunks, 4 heads, SJ j-splits). No barriers, no rescaling:
// fixed shift m_ih = leaky(el_i + max_all_j er_jh) makes j-splits additive.
// den comes free from an MFMA against an all-ones B fragment.
// ---------------------------------------------------------------------------
__global__ __launch_bounds__(256, 4) void k_gat(
    const int* __restrict__ adj, const unsigned short* __restrict__ hT,
    const float* __restrict__ el_t, const float* __restrict__ er_t,
    const unsigned* __restrict__ M_enc,
    float* __restrict__ nump, float* __restrict__ denp, int jlen)
{
  const int tid = threadIdx.x;
  const int wid = tid >> 6, lane = tid & 63;
  const int l15 = lane & 15, lg = lane >> 4;
  const int bx = blockIdx.x;
  const int h  = blockIdx.y;
  const int js = blockIdx.z;
  const int i0 = bx * 64 + wid * 16;
  const int j0 = js * jlen;

  const int irow = i0 + l15;
  const float el  = el_t[h * NNODES + irow];
  const float M   = decf(M_enc[h]);
  const float sE  = el + M;
  const float mih = fmaxf(sE, NEG * sE);   // leaky(el_i + max er) >= all masked scores

  const int*            adjp = adj + (size_t)irow * NNODES + j0 + lg * 8;
  const float*          erp  = er_t + h * NNODES + j0 + lg * 8;
  const unsigned short* hp   = hT + (size_t)(h * 64 + l15) * NNODES + j0 + lg * 8;

  f32x4 acc0 = {0.f,0.f,0.f,0.f}, acc1 = {0.f,0.f,0.f,0.f};
  f32x4 acc2 = {0.f,0.f,0.f,0.f}, acc3 = {0.f,0.f,0.f,0.f};
  f32x4 accd = {0.f,0.f,0.f,0.f};
  s16x8 ones;
#pragma unroll
  for (int e = 0; e < 8; ++e) ones[e] = (short)0x3F80;  // bf16 1.0

  for (int jb = 0; jb < jlen; jb += 32) {
    i32x4 a0 = *(const i32x4*)(adjp);
    i32x4 a1 = *(const i32x4*)(adjp + 4);
    f32x4 e0 = *(const f32x4*)(erp);
    f32x4 e1 = *(const f32x4*)(erp + 4);
    float w[8];
#pragma unroll
    for (int e = 0; e < 4; ++e) {
      float s  = el + e0[e];
      float l  = fmaxf(s, NEG * s);        // leaky_relu (slope<1)
      float ww = __expf(l - mih);
      w[e] = (a0[e] > 0) ? ww : 0.f;
    }
#pragma unroll
    for (int e = 0; e < 4; ++e) {
      float s  = el + e1[e];
      float l  = fmaxf(s, NEG * s);
      float ww = __expf(l - mih);
      w[4 + e] = (a1[e] > 0) ? ww : 0.f;
    }
    union { s16x8 v; unsigned short u[8]; } af;
#pragma unroll
    for (int e = 0; e < 8; ++e) af.u[e] = f2bf(w[e]);

    s16x8 b0 = *(const s16x8*)(hp);
    s16x8 b1 = *(const s16x8*)(hp + 16 * NNODES);
    s16x8 b2 = *(const s16x8*)(hp + 32 * NNODES);
    s16x8 b3 = *(const s16x8*)(hp + 48 * NNODES);

    acc0 = __builtin_amdgcn_mfma_f32_16x16x32_bf16(af.v, b0,   acc0, 0, 0, 0);
    acc1 = __builtin_amdgcn_mfma_f32_16x16x32_bf16(af.v, b1,   acc1, 0, 0, 0);
    acc2 = __builtin_amdgcn_mfma_f32_16x16x32_bf16(af.v, b2,   acc2, 0, 0, 0);
    acc3 = __builtin_amdgcn_mfma_f32_16x16x32_bf16(af.v, b3,   acc3, 0, 0, 0);
    accd = __builtin_amdgcn_mfma_f32_16x16x32_bf16(af.v, ones, accd, 0, 0, 0);

    adjp += 32; erp += 32; hp += 32;
  }

  // C/D layout: col = lane&15, row = (lane>>4)*4 + reg  [verified m89]
  const int orow = i0 + lg * 4;
  float* np = nump + ((size_t)js * NNODES + orow) * OUTF + h * 64 + l15;
#pragma unroll
  for (int r = 0; r < 4; ++r) {
    np[r * OUTF +  0] = acc0[r];
    np[r * OUTF + 16] = acc1[r];
    np[r * OUTF + 32] = acc2[r];
    np[r * OUTF + 48] = acc3[r];
  }
  if (l15 == 0) {
    float* dp = denp + ((size_t)js * NNODES + orow) * 4 + h;
#pragma unroll
    for (int r = 0; r < 4; ++r) dp[r * 4] = accd[r];
  }
}

// ---------------------------------------------------------------------------
// Kernel C: sum j-split partials, divide by den, add bias.
// ---------------------------------------------------------------------------
__global__ __launch_bounds__(256) void k_div(
    const float* __restrict__ nump, const float* __restrict__ denp,
    const float* __restrict__ bias, float* __restrict__ out, int sj)
{
  const int q  = blockIdx.x * 256 + threadIdx.x;  // float4 index
  const int n  = q >> 6;
  const int c4 = (q & 63) * 4;
  const int h  = c4 >> 6;
  f32x4 s = {0.f, 0.f, 0.f, 0.f};
  float d = 0.f;
  for (int t = 0; t < sj; ++t) {
    s += *(const f32x4*)(nump + ((size_t)t * NNODES + n) * OUTF + c4);
    d += denp[((size_t)t * NNODES + n) * 4 + h];
  }
  f32x4 b = *(const f32x4*)(bias + c4);
  float r = __builtin_amdgcn_rcpf(d);
  f32x4 o = s * r + b;
  *(f32x4*)(out + (size_t)n * OUTF + c4) = o;
}

extern "C" void kernel_launch(void* const* d_in, const int* in_sizes, int n_in,
                              void* d_out, int out_size, void* d_ws, size_t ws_size,
                              hipStream_t stream)
{
  const float* x    = (const float*)d_in[0];
  const int*   adj  = (const int*)d_in[1];
  const float* W    = (const float*)d_in[2];
  const float* attl = (const float*)d_in[3];
  const float* attr = (const float*)d_in[4];
  const float* bias = (const float*)d_in[5];
  float* out = (float*)d_out;
  char*  ws  = (char*)d_ws;

  // workspace layout
  unsigned short* hT  = (unsigned short*)ws;                        // 2 MB
  float*    el_t  = (float*)(ws + (2u << 20));                      // 64 KB
  float*    er_t  = (float*)(ws + (2u << 20) + (64u << 10));        // 64 KB
  unsigned* M_enc = (unsigned*)(ws + (2u << 20) + (128u << 10));    // 16 B
  float*    denp  = (float*)(ws + (2u << 20) + (192u << 10));       // <=256 KB
  const size_t nbase = (3u << 20);

  int sj = 4;
  if (ws_size < nbase + (size_t)4 * NNODES * OUTF * 4) {
    sj = (ws_size >= nbase + (size_t)2 * NNODES * OUTF * 4) ? 2 : 1;
  }
  float* nump = (sj == 1) ? out : (float*)(ws + nbase);

  hipMemsetAsync(M_enc, 0, 16, stream);
  k_feat<<<dim3(4, 64), 256, 0, stream>>>(x, W, attl, attr, hT, el_t, er_t, M_enc);
  k_gat<<<dim3(64, 4, sj), 256, 0, stream>>>(adj, hT, el_t, er_t, M_enc, nump, denp, NNODES / sj);
  k_div<<<dim3(1024), 256, 0, stream>>>(nump, denp, bias, out, sj);
}

// Round 2
// 121.121 us; speedup vs baseline: 1.1203x; 1.1203x over previous
//
#include <hip/hip_runtime.h>
#include <hip/hip_bf16.h>
#include <stdint.h>

typedef float f32x4 __attribute__((ext_vector_type(4)));
typedef short s16x8 __attribute__((ext_vector_type(8)));
typedef int   i32x4 __attribute__((ext_vector_type(4)));
typedef unsigned int u32;

#define NNODES 4096
#define INC    256
#define OUTF   256
#define NEG    0.2f

__device__ __forceinline__ unsigned short f2bf(float f) {
  unsigned u = __float_as_uint(f);
  u += 0x7FFFu + ((u >> 16) & 1u);          // RNE
  return (unsigned short)(u >> 16);
}
__device__ __forceinline__ unsigned encf(float x) {
  unsigned u = __float_as_uint(x);
  return (u & 0x80000000u) ? ~u : (u | 0x80000000u);
}
__device__ __forceinline__ float decf(unsigned e) {
  unsigned u = (e & 0x80000000u) ? (e ^ 0x80000000u) : ~e;
  return __uint_as_float(u);
}

// ---------------------------------------------------------------------------
// Kernel A: h = x @ W (f32), write hT (bf16, [c][n]), el logits (f32),
// QS = packed (bf16 exp(0.2*er) << 16 | bf16 exp(er)) per (h, j),
// and atomicMax of global er max per head.
// ---------------------------------------------------------------------------
__global__ __launch_bounds__(256) void k_feat(
    const float* __restrict__ x, const float* __restrict__ W,
    const float* __restrict__ attl, const float* __restrict__ attr,
    unsigned short* __restrict__ hT, float* __restrict__ el_t,
    u32* __restrict__ QS, unsigned* __restrict__ M_enc)
{
  __shared__ float sm[4352];
  float* xs  = sm;          // [32][68]
  float* wsl = sm + 2176;   // [32][68]
  const int tid = threadIdx.x;
  const int hb = blockIdx.x, nb = blockIdx.y;
  const int n0 = nb * 64, c0 = hb * 64;
  const int ty = tid >> 4, tx = tid & 15;

  float acc[4][4];
#pragma unroll
  for (int r = 0; r < 4; ++r)
#pragma unroll
    for (int j = 0; j < 4; ++j) acc[r][j] = 0.f;

  const int sn = tid >> 2, sko = (tid & 3) * 8;
  const int wk = tid >> 3, wco = (tid & 7) * 8;

  for (int kc = 0; kc < INC; kc += 32) {
    __syncthreads();
    {
      const float* xp = x + (size_t)(n0 + sn) * INC + kc + sko;
      float4 a = *(const float4*)xp;
      float4 b = *(const float4*)(xp + 4);
      xs[(sko + 0) * 68 + sn] = a.x; xs[(sko + 1) * 68 + sn] = a.y;
      xs[(sko + 2) * 68 + sn] = a.z; xs[(sko + 3) * 68 + sn] = a.w;
      xs[(sko + 4) * 68 + sn] = b.x; xs[(sko + 5) * 68 + sn] = b.y;
      xs[(sko + 6) * 68 + sn] = b.z; xs[(sko + 7) * 68 + sn] = b.w;
      const float* wp = W + (size_t)(kc + wk) * OUTF + c0 + wco;
      *(float4*)(wsl + wk * 68 + wco)     = *(const float4*)wp;
      *(float4*)(wsl + wk * 68 + wco + 4) = *(const float4*)(wp + 4);
    }
    __syncthreads();
#pragma unroll
    for (int k = 0; k < 32; ++k) {
      float4 a = *(const float4*)(xs + k * 68 + ty * 4);
      float4 b = *(const float4*)(wsl + k * 68 + tx * 4);
      acc[0][0] = fmaf(a.x, b.x, acc[0][0]); acc[0][1] = fmaf(a.x, b.y, acc[0][1]);
      acc[0][2] = fmaf(a.x, b.z, acc[0][2]); acc[0][3] = fmaf(a.x, b.w, acc[0][3]);
      acc[1][0] = fmaf(a.y, b.x, acc[1][0]); acc[1][1] = fmaf(a.y, b.y, acc[1][1]);
      acc[1][2] = fmaf(a.y, b.z, acc[1][2]); acc[1][3] = fmaf(a.y, b.w, acc[1][3]);
      acc[2][0] = fmaf(a.z, b.x, acc[2][0]); acc[2][1] = fmaf(a.z, b.y, acc[2][1]);
      acc[2][2] = fmaf(a.z, b.z, acc[2][2]); acc[2][3] = fmaf(a.z, b.w, acc[2][3]);
      acc[3][0] = fmaf(a.w, b.x, acc[3][0]); acc[3][1] = fmaf(a.w, b.y, acc[3][1]);
      acc[3][2] = fmaf(a.w, b.z, acc[3][2]); acc[3][3] = fmaf(a.w, b.w, acc[3][3]);
    }
  }

  float4 al = *(const float4*)(attl + c0 + tx * 4);
  float4 ar = *(const float4*)(attr + c0 + tx * 4);
  float pl[4], pr[4];
#pragma unroll
  for (int r = 0; r < 4; ++r) {
    pl[r] = acc[r][0] * al.x + acc[r][1] * al.y + acc[r][2] * al.z + acc[r][3] * al.w;
    pr[r] = acc[r][0] * ar.x + acc[r][1] * ar.y + acc[r][2] * ar.z + acc[r][3] * ar.w;
  }
#pragma unroll
  for (int m = 1; m < 16; m <<= 1) {
#pragma unroll
    for (int r = 0; r < 4; ++r) {
      pl[r] += __shfl_xor(pl[r], m, 64);
      pr[r] += __shfl_xor(pr[r], m, 64);
    }
  }
  if (tx == 0) {
#pragma unroll
    for (int r = 0; r < 4; ++r) {
      el_t[hb * NNODES + n0 + ty * 4 + r] = pl[r];
      float q = __expf(pr[r]);
      float s = __expf(NEG * pr[r]);
      QS[hb * NNODES + n0 + ty * 4 + r] = (u32)f2bf(q) | ((u32)f2bf(s) << 16);
    }
  }
  float mx = fmaxf(fmaxf(pr[0], pr[1]), fmaxf(pr[2], pr[3]));
  mx = fmaxf(mx, __shfl_xor(mx, 16, 64));
  mx = fmaxf(mx, __shfl_xor(mx, 32, 64));
  if ((tid & 63) == 0) atomicMax(M_enc + hb, encf(mx));

  __syncthreads();
#pragma unroll
  for (int r = 0; r < 4; ++r)
#pragma unroll
    for (int j = 0; j < 4; ++j)
      sm[(tx * 4 + j) * 68 + ty * 4 + r] = acc[r][j];
  __syncthreads();
  {
    const int c = tid >> 2, ns = (tid & 3) * 16;
    unsigned v[8];
#pragma unroll
    for (int i = 0; i < 8; ++i) {
      unsigned lo = f2bf(sm[c * 68 + ns + 2 * i]);
      unsigned hi = f2bf(sm[c * 68 + ns + 2 * i + 1]);
      v[i] = lo | (hi << 16);
    }
    unsigned short* dst = hT + (size_t)(c0 + c) * NNODES + n0 + ns;
    *(uint4*)(dst)     = make_uint4(v[0], v[1], v[2], v[3]);
    *(uint4*)(dst + 8) = make_uint4(v[4], v[5], v[6], v[7]);
  }
}

// ---------------------------------------------------------------------------
// Kernel B: fused masked-softmax + PV. One wave = 16 i-rows x ALL 4 heads:
// adj streamed from HBM exactly once, amortized over 4 heads x 5 MFMAs.
// w = max(P_i*Q_j, R_i*S_j) (exact leaky-softmax factorization), Q/S bf16.
// Register double-buffer on the adj stream; raw s_barrier keeps the 4 waves
// of a block (4 i-chunks, same j-slab) in lockstep for L1 hT/QS sharing
// without draining vmcnt.
// ---------------------------------------------------------------------------
__global__ __launch_bounds__(256) void k_gat(
    const int* __restrict__ adj, const unsigned short* __restrict__ hT,
    const float* __restrict__ el_t, const u32* __restrict__ QS,
    const unsigned* __restrict__ M_enc,
    float* __restrict__ nump, float* __restrict__ denp, int jlen)
{
  const int tid = threadIdx.x;
  const int wid = tid >> 6, lane = tid & 63;
  const int l15 = lane & 15, lg = lane >> 4;
  const int i0 = (blockIdx.x * 4 + wid) * 16;
  const int js = blockIdx.y;
  const int j0 = js * jlen;
  const int irow = i0 + l15;

  float P[4], Rr[4];
#pragma unroll
  for (int h = 0; h < 4; ++h) {
    float el  = el_t[h * NNODES + irow];
    float M   = decf(M_enc[h]);
    float sE  = el + M;
    float mih = fmaxf(sE, NEG * sE);
    P[h]  = __expf(el - mih);
    Rr[h] = __expf(NEG * el - mih);
  }

  const int*            adjp = adj + (size_t)irow * NNODES + j0 + lg * 8;
  const u32*            qsp  = QS + j0 + lg * 8;
  const unsigned short* hp   = hT + (size_t)l15 * NNODES + j0 + lg * 8;

  f32x4 acc[4][4];
  f32x4 accd[4];
#pragma unroll
  for (int h = 0; h < 4; ++h) {
    accd[h] = (f32x4){0.f, 0.f, 0.f, 0.f};
#pragma unroll
    for (int c = 0; c < 4; ++c) acc[h][c] = (f32x4){0.f, 0.f, 0.f, 0.f};
  }
  s16x8 ones;
#pragma unroll
  for (int e = 0; e < 8; ++e) ones[e] = (short)0x3F80;  // bf16 1.0

  i32x4 a0 = *(const i32x4*)(adjp);
  i32x4 a1 = *(const i32x4*)(adjp + 4);

  const int niter = jlen >> 5;
  for (int it = 0; it < niter; ++it) {
    // prefetch next adj chunk (HBM/LLC stream) while computing current
    const int* pf = adjp + ((it + 1 < niter) ? 32 : 0);
    i32x4 na0 = *(const i32x4*)(pf);
    i32x4 na1 = *(const i32x4*)(pf + 4);

#pragma unroll
    for (int h = 0; h < 4; ++h) {
      const u32* qh = qsp + h * NNODES;
      i32x4 u0 = *(const i32x4*)(qh);
      i32x4 u1 = *(const i32x4*)(qh + 4);
      const unsigned short* hh = hp + (size_t)(h * 64) * NNODES;
      s16x8 b0 = *(const s16x8*)(hh);
      s16x8 b1 = *(const s16x8*)(hh + (size_t)16 * NNODES);
      s16x8 b2 = *(const s16x8*)(hh + (size_t)32 * NNODES);
      s16x8 b3 = *(const s16x8*)(hh + (size_t)48 * NNODES);

      float w[8];
#pragma unroll
      for (int e = 0; e < 4; ++e) {
        u32 m0 = (a0[e] > 0) ? (u32)u0[e] : 0u;
        u32 m1 = (a1[e] > 0) ? (u32)u1[e] : 0u;
        float q0 = __uint_as_float(m0 << 16);
        float s0 = __uint_as_float(m0 & 0xffff0000u);
        float q1 = __uint_as_float(m1 << 16);
        float s1 = __uint_as_float(m1 & 0xffff0000u);
        w[e]     = fmaxf(P[h] * q0, Rr[h] * s0);
        w[e + 4] = fmaxf(P[h] * q1, Rr[h] * s1);
      }
      union { u32 uu[4]; s16x8 v; } af;
#pragma unroll
      for (int p = 0; p < 4; ++p)
        asm("v_cvt_pk_bf16_f32 %0, %1, %2" : "=v"(af.uu[p]) : "v"(w[2 * p]), "v"(w[2 * p + 1]));

      acc[h][0] = __builtin_amdgcn_mfma_f32_16x16x32_bf16(af.v, b0,   acc[h][0], 0, 0, 0);
      acc[h][1] = __builtin_amdgcn_mfma_f32_16x16x32_bf16(af.v, b1,   acc[h][1], 0, 0, 0);
      acc[h][2] = __builtin_amdgcn_mfma_f32_16x16x32_bf16(af.v, b2,   acc[h][2], 0, 0, 0);
      acc[h][3] = __builtin_amdgcn_mfma_f32_16x16x32_bf16(af.v, b3,   acc[h][3], 0, 0, 0);
      accd[h]   = __builtin_amdgcn_mfma_f32_16x16x32_bf16(af.v, ones, accd[h],   0, 0, 0);
    }

    a0 = na0; a1 = na1;
    adjp += 32; qsp += 32; hp += 32;
    __builtin_amdgcn_s_barrier();   // raw: lockstep for L1 sharing, no vmcnt drain
  }

  // C/D layout: col = lane&15, row = (lane>>4)*4 + reg
  const int orow = i0 + lg * 4;
  float* np = nump + ((size_t)js * NNODES + orow) * OUTF + l15;
#pragma unroll
  for (int h = 0; h < 4; ++h)
#pragma unroll
    for (int c = 0; c < 4; ++c)
#pragma unroll
      for (int r = 0; r < 4; ++r)
        np[r * OUTF + h * 64 + c * 16] = acc[h][c][r];

  if (l15 == 0) {
    float* dp = denp + ((size_t)js * NNODES + orow) * 4;
#pragma unroll
    for (int h = 0; h < 4; ++h)
#pragma unroll
      for (int r = 0; r < 4; ++r) dp[r * 4 + h] = accd[h][r];
  }
}

// ---------------------------------------------------------------------------
// Kernel C: sum j-split partials, divide by den, add bias.
// ---------------------------------------------------------------------------
__global__ __launch_bounds__(256) void k_div(
    const float* __restrict__ nump, const float* __restrict__ denp,
    const float* __restrict__ bias, float* __restrict__ out, int sj)
{
  const int q  = blockIdx.x * 256 + threadIdx.x;  // float4 index
  const int n  = q >> 6;
  const int c4 = (q & 63) * 4;
  const int h  = c4 >> 6;
  f32x4 s = {0.f, 0.f, 0.f, 0.f};
  float d = 0.f;
  for (int t = 0; t < sj; ++t) {
    s += *(const f32x4*)(nump + ((size_t)t * NNODES + n) * OUTF + c4);
    d += denp[((size_t)t * NNODES + n) * 4 + h];
  }
  f32x4 b = *(const f32x4*)(bias + c4);
  float r = __builtin_amdgcn_rcpf(d);
  f32x4 o = s * r + b;
  *(f32x4*)(out + (size_t)n * OUTF + c4) = o;
}

extern "C" void kernel_launch(void* const* d_in, const int* in_sizes, int n_in,
                              void* d_out, int out_size, void* d_ws, size_t ws_size,
                              hipStream_t stream)
{
  const float* x    = (const float*)d_in[0];
  const int*   adj  = (const int*)d_in[1];
  const float* W    = (const float*)d_in[2];
  const float* attl = (const float*)d_in[3];
  const float* attr = (const float*)d_in[4];
  const float* bias = (const float*)d_in[5];
  float* out = (float*)d_out;
  char*  ws  = (char*)d_ws;

  // workspace layout
  unsigned short* hT  = (unsigned short*)ws;                        // 2 MB
  float*    el_t  = (float*)(ws + (2u << 20));                      // 64 KB
  u32*      QS    = (u32*)(ws + (2u << 20) + (64u << 10));          // 64 KB
  unsigned* M_enc = (unsigned*)(ws + (2u << 20) + (128u << 10));    // 16 B
  float*    denp  = (float*)(ws + (2u << 20) + (192u << 10));       // <=512 KB
  const size_t nbase = (3u << 20);

  const size_t per_split = (size_t)NNODES * OUTF * 4;
  int sj = 8;
  while (sj > 1 && ws_size < nbase + (size_t)sj * per_split) sj >>= 1;
  float* nump = (sj == 1) ? out : (float*)(ws + nbase);

  hipMemsetAsync(M_enc, 0, 16, stream);
  k_feat<<<dim3(4, 64), 256, 0, stream>>>(x, W, attl, attr, hT, el_t, QS, M_enc);
  k_gat<<<dim3(64, sj), 256, 0, stream>>>(adj, hT, el_t, QS, M_enc, nump, denp, NNODES / sj);
  k_div<<<dim3(1024), 256, 0, stream>>>(nump, denp, bias, out, sj);
}

// Round 3
// 78.619 us; speedup vs baseline: 1.7260x; 1.5406x over previous
//
#include <hip/hip_runtime.h>
#include <hip/hip_bf16.h>
#include <stdint.h>

typedef float f32x4 __attribute__((ext_vector_type(4)));
typedef short s16x8 __attribute__((ext_vector_type(8)));
typedef int   i32x4 __attribute__((ext_vector_type(4)));
typedef unsigned int u32;

#define NNODES 4096
#define INC    256
#define OUTF   256
#define NEG    0.2f

__device__ __forceinline__ unsigned short f2bf(float f) {
  unsigned u = __float_as_uint(f);
  u += 0x7FFFu + ((u >> 16) & 1u);          // RNE
  return (unsigned short)(u >> 16);
}
__device__ __forceinline__ unsigned encf(float x) {
  unsigned u = __float_as_uint(x);
  return (u & 0x80000000u) ? ~u : (u | 0x80000000u);
}
__device__ __forceinline__ float decf(unsigned e) {
  unsigned u = (e & 0x80000000u) ? (e ^ 0x80000000u) : ~e;
  return __uint_as_float(u);
}

// ---------------------------------------------------------------------------
// Kernel A: h = x @ W (f32), write hT (bf16, [c][n], GRANULE-SWIZZLED within
// each 32-n block: granule g of row c stored at g ^ ((c&3)^((c>>2)&3)) so that
// k_gat's linear global_load_lds + swizzled ds_read is bank-conflict-free),
// el logits (f32), QS = packed (bf16 exp(0.2*er) << 16 | bf16 exp(er)),
// and atomicMax of global er max per head.
// ---------------------------------------------------------------------------
__global__ __launch_bounds__(256) void k_feat(
    const float* __restrict__ x, const float* __restrict__ W,
    const float* __restrict__ attl, const float* __restrict__ attr,
    unsigned short* __restrict__ hT, float* __restrict__ el_t,
    u32* __restrict__ QS, unsigned* __restrict__ M_enc)
{
  __shared__ float sm[4352];
  float* xs  = sm;          // [32][68]
  float* wsl = sm + 2176;   // [32][68]
  const int tid = threadIdx.x;
  const int hb = blockIdx.x, nb = blockIdx.y;
  const int n0 = nb * 64, c0 = hb * 64;
  const int ty = tid >> 4, tx = tid & 15;

  float acc[4][4];
#pragma unroll
  for (int r = 0; r < 4; ++r)
#pragma unroll
    for (int j = 0; j < 4; ++j) acc[r][j] = 0.f;

  const int sn = tid >> 2, sko = (tid & 3) * 8;
  const int wk = tid >> 3, wco = (tid & 7) * 8;

  for (int kc = 0; kc < INC; kc += 32) {
    __syncthreads();
    {
      const float* xp = x + (size_t)(n0 + sn) * INC + kc + sko;
      float4 a = *(const float4*)xp;
      float4 b = *(const float4*)(xp + 4);
      xs[(sko + 0) * 68 + sn] = a.x; xs[(sko + 1) * 68 + sn] = a.y;
      xs[(sko + 2) * 68 + sn] = a.z; xs[(sko + 3) * 68 + sn] = a.w;
      xs[(sko + 4) * 68 + sn] = b.x; xs[(sko + 5) * 68 + sn] = b.y;
      xs[(sko + 6) * 68 + sn] = b.z; xs[(sko + 7) * 68 + sn] = b.w;
      const float* wp = W + (size_t)(kc + wk) * OUTF + c0 + wco;
      *(float4*)(wsl + wk * 68 + wco)     = *(const float4*)wp;
      *(float4*)(wsl + wk * 68 + wco + 4) = *(const float4*)(wp + 4);
    }
    __syncthreads();
#pragma unroll
    for (int k = 0; k < 32; ++k) {
      float4 a = *(const float4*)(xs + k * 68 + ty * 4);
      float4 b = *(const float4*)(wsl + k * 68 + tx * 4);
      acc[0][0] = fmaf(a.x, b.x, acc[0][0]); acc[0][1] = fmaf(a.x, b.y, acc[0][1]);
      acc[0][2] = fmaf(a.x, b.z, acc[0][2]); acc[0][3] = fmaf(a.x, b.w, acc[0][3]);
      acc[1][0] = fmaf(a.y, b.x, acc[1][0]); acc[1][1] = fmaf(a.y, b.y, acc[1][1]);
      acc[1][2] = fmaf(a.y, b.z, acc[1][2]); acc[1][3] = fmaf(a.y, b.w, acc[1][3]);
      acc[2][0] = fmaf(a.z, b.x, acc[2][0]); acc[2][1] = fmaf(a.z, b.y, acc[2][1]);
      acc[2][2] = fmaf(a.z, b.z, acc[2][2]); acc[2][3] = fmaf(a.z, b.w, acc[2][3]);
      acc[3][0] = fmaf(a.w, b.x, acc[3][0]); acc[3][1] = fmaf(a.w, b.y, acc[3][1]);
      acc[3][2] = fmaf(a.w, b.z, acc[3][2]); acc[3][3] = fmaf(a.w, b.w, acc[3][3]);
    }
  }

  float4 al = *(const float4*)(attl + c0 + tx * 4);
  float4 ar = *(const float4*)(attr + c0 + tx * 4);
  float pl[4], pr[4];
#pragma unroll
  for (int r = 0; r < 4; ++r) {
    pl[r] = acc[r][0] * al.x + acc[r][1] * al.y + acc[r][2] * al.z + acc[r][3] * al.w;
    pr[r] = acc[r][0] * ar.x + acc[r][1] * ar.y + acc[r][2] * ar.z + acc[r][3] * ar.w;
  }
#pragma unroll
  for (int m = 1; m < 16; m <<= 1) {
#pragma unroll
    for (int r = 0; r < 4; ++r) {
      pl[r] += __shfl_xor(pl[r], m, 64);
      pr[r] += __shfl_xor(pr[r], m, 64);
    }
  }
  if (tx == 0) {
#pragma unroll
    for (int r = 0; r < 4; ++r) {
      el_t[hb * NNODES + n0 + ty * 4 + r] = pl[r];
      float q = __expf(pr[r]);
      float s = __expf(NEG * pr[r]);
      QS[hb * NNODES + n0 + ty * 4 + r] = (u32)f2bf(q) | ((u32)f2bf(s) << 16);
    }
  }
  float mx = fmaxf(fmaxf(pr[0], pr[1]), fmaxf(pr[2], pr[3]));
  mx = fmaxf(mx, __shfl_xor(mx, 16, 64));
  mx = fmaxf(mx, __shfl_xor(mx, 32, 64));
  if ((tid & 63) == 0) atomicMax(M_enc + hb, encf(mx));

  __syncthreads();
#pragma unroll
  for (int r = 0; r < 4; ++r)
#pragma unroll
    for (int j = 0; j < 4; ++j)
      sm[(tx * 4 + j) * 68 + ty * 4 + r] = acc[r][j];
  __syncthreads();
  {
    const int c = tid >> 2, ns = (tid & 3) * 16;
    unsigned v[8];
#pragma unroll
    for (int i = 0; i < 8; ++i) {
      unsigned lo = f2bf(sm[c * 68 + ns + 2 * i]);
      unsigned hi = f2bf(sm[c * 68 + ns + 2 * i + 1]);
      v[i] = lo | (hi << 16);
    }
    // swizzled store: granule g (8 n) of 32-n block at position g ^ sw(c)
    const int sw = (c & 3) ^ ((c >> 2) & 3);
    const int blk = n0 + (ns & 32);
    const int g0 = (ns & 16) >> 3;          // 0 or 2
    unsigned short* dstb = hT + (size_t)(c0 + c) * NNODES + blk;
    *(uint4*)(dstb + ((g0 ^ sw) * 8))       = make_uint4(v[0], v[1], v[2], v[3]);
    *(uint4*)(dstb + (((g0 + 1) ^ sw) * 8)) = make_uint4(v[4], v[5], v[6], v[7]);
  }
}

// ---------------------------------------------------------------------------
// Kernel B: fused masked-softmax + PV. One wave = 16 i-rows x ALL 4 heads.
// hT staged through LDS (16KB/iter/block, global_load_lds width=16, linear
// dest; global is pre-swizzled so swizzled ds_read is ~conflict-free),
// shared by all 4 waves. 2-phase pipeline: fill(next) -> compute(cur) ->
// vmcnt(0)+barrier. adj + QS register-prefetched one iteration ahead.
// w = max(P_i*Q_j, R_i*S_j) exact leaky-softmax factorization; den via
// MFMA against all-ones B.
// ---------------------------------------------------------------------------
__global__ __launch_bounds__(256) void k_gat(
    const int* __restrict__ adj, const unsigned short* __restrict__ hT,
    const float* __restrict__ el_t, const u32* __restrict__ QS,
    const unsigned* __restrict__ M_enc,
    float* __restrict__ nump, float* __restrict__ denp, int jlen)
{
  __shared__ __align__(16) unsigned short hbuf[2][8192];   // 2 x 16KB: [256 rows][32 bf16]
  const int tid = threadIdx.x;
  const int wid = tid >> 6, lane = tid & 63;
  const int l15 = lane & 15, lg = lane >> 4;
  const int i0 = (blockIdx.x * 4 + wid) * 16;
  const int js = blockIdx.y;
  const int j0 = js * jlen;
  const int irow = i0 + l15;
  const int sw_l = (l15 & 3) ^ ((l15 >> 2) & 3);

  float P[4], Rr[4];
#pragma unroll
  for (int h = 0; h < 4; ++h) {
    float el  = el_t[h * NNODES + irow];
    float M   = decf(M_enc[h]);
    float sE  = el + M;
    float mih = fmaxf(sE, NEG * sE);
    P[h]  = __expf(el - mih);
    Rr[h] = __expf(NEG * el - mih);
  }

  const int*            adjp = adj + (size_t)irow * NNODES + j0 + lg * 8;
  const u32*            qsp  = QS + j0 + lg * 8;
  // fill source: wave wid covers rows wid*64 .. wid*64+63 (4 instrs x 16 rows)
  const unsigned short* hsrc = hT + (size_t)(wid * 64 + (lane >> 2)) * NNODES + j0 + (lane & 3) * 8;

  f32x4 acc[4][4];
  f32x4 accd[4];
#pragma unroll
  for (int h = 0; h < 4; ++h) {
    accd[h] = (f32x4){0.f, 0.f, 0.f, 0.f};
#pragma unroll
    for (int c = 0; c < 4; ++c) acc[h][c] = (f32x4){0.f, 0.f, 0.f, 0.f};
  }
  s16x8 ones;
#pragma unroll
  for (int e = 0; e < 8; ++e) ones[e] = (short)0x3F80;  // bf16 1.0

  const int niter = jlen >> 5;

  // prologue: fill buf0 (j-block 0)
#pragma unroll
  for (int q = 0; q < 4; ++q)
    __builtin_amdgcn_global_load_lds(hsrc + (size_t)q * 16 * NNODES,
                                     &hbuf[0][wid * 2048 + q * 512], 16, 0, 0);
  // prefetch adj + QS for iter 0
  i32x4 a0 = *(const i32x4*)(adjp);
  i32x4 a1 = *(const i32x4*)(adjp + 4);
  i32x4 u0[4], u1[4];
#pragma unroll
  for (int h = 0; h < 4; ++h) {
    u0[h] = *(const i32x4*)(qsp + h * NNODES);
    u1[h] = *(const i32x4*)(qsp + h * NNODES + 4);
  }
  asm volatile("s_waitcnt vmcnt(0)" ::: "memory");
  __builtin_amdgcn_s_barrier();

  for (int it = 0; it < niter; ++it) {
    const int cur = it & 1;
    const bool hasnext = (it + 1 < niter);
    const int tn = hasnext ? (it + 1) : it;

    // issue fill of next buffer (overlaps with this iter's compute)
    if (hasnext) {
      const unsigned short* hs = hsrc + (size_t)(it + 1) * 32;
#pragma unroll
      for (int q = 0; q < 4; ++q)
        __builtin_amdgcn_global_load_lds(hs + (size_t)q * 16 * NNODES,
                                         &hbuf[cur ^ 1][wid * 2048 + q * 512], 16, 0, 0);
    }
    // register-prefetch next adj + QS
    const int* ap = adjp + tn * 32;
    i32x4 na0 = *(const i32x4*)(ap);
    i32x4 na1 = *(const i32x4*)(ap + 4);
    i32x4 nu0[4], nu1[4];
#pragma unroll
    for (int h = 0; h < 4; ++h) {
      const u32* qh = qsp + h * NNODES + tn * 32;
      nu0[h] = *(const i32x4*)(qh);
      nu1[h] = *(const i32x4*)(qh + 4);
    }

#pragma unroll
    for (int h = 0; h < 4; ++h) {
      // B-frags from LDS (swizzled read, ~2-way bank aliasing = free)
      const unsigned short* lb = &hbuf[cur][(h * 64 + l15) * 32 + ((lg ^ sw_l) * 8)];
      s16x8 b0 = *(const s16x8*)(lb);
      s16x8 b1 = *(const s16x8*)(lb + 16 * 32);
      s16x8 b2 = *(const s16x8*)(lb + 32 * 32);
      s16x8 b3 = *(const s16x8*)(lb + 48 * 32);

      float w[8];
#pragma unroll
      for (int e = 0; e < 4; ++e) {
        u32 m0 = (a0[e] > 0) ? (u32)u0[h][e] : 0u;
        u32 m1 = (a1[e] > 0) ? (u32)u1[h][e] : 0u;
        float q0 = __uint_as_float(m0 << 16);
        float s0 = __uint_as_float(m0 & 0xffff0000u);
        float q1 = __uint_as_float(m1 << 16);
        float s1 = __uint_as_float(m1 & 0xffff0000u);
        w[e]     = fmaxf(P[h] * q0, Rr[h] * s0);
        w[e + 4] = fmaxf(P[h] * q1, Rr[h] * s1);
      }
      union { u32 uu[4]; s16x8 v; } af;
#pragma unroll
      for (int p = 0; p < 4; ++p)
        asm("v_cvt_pk_bf16_f32 %0, %1, %2" : "=v"(af.uu[p]) : "v"(w[2 * p]), "v"(w[2 * p + 1]));

      acc[h][0] = __builtin_amdgcn_mfma_f32_16x16x32_bf16(af.v, b0,   acc[h][0], 0, 0, 0);
      acc[h][1] = __builtin_amdgcn_mfma_f32_16x16x32_bf16(af.v, b1,   acc[h][1], 0, 0, 0);
      acc[h][2] = __builtin_amdgcn_mfma_f32_16x16x32_bf16(af.v, b2,   acc[h][2], 0, 0, 0);
      acc[h][3] = __builtin_amdgcn_mfma_f32_16x16x32_bf16(af.v, b3,   acc[h][3], 0, 0, 0);
      accd[h]   = __builtin_amdgcn_mfma_f32_16x16x32_bf16(af.v, ones, accd[h],   0, 0, 0);
    }

    a0 = na0; a1 = na1;
#pragma unroll
    for (int h = 0; h < 4; ++h) { u0[h] = nu0[h]; u1[h] = nu1[h]; }

    // drain next-fill (latency was covered by compute above), then sync
    asm volatile("s_waitcnt vmcnt(0)" ::: "memory");
    __builtin_amdgcn_s_barrier();
  }

  // C/D layout: col = lane&15, row = (lane>>4)*4 + reg
  const int orow = i0 + lg * 4;
  float* np = nump + ((size_t)js * NNODES + orow) * OUTF + l15;
#pragma unroll
  for (int h = 0; h < 4; ++h)
#pragma unroll
    for (int c = 0; c < 4; ++c)
#pragma unroll
      for (int r = 0; r < 4; ++r)
        np[r * OUTF + h * 64 + c * 16] = acc[h][c][r];

  if (l15 == 0) {
    float* dp = denp + ((size_t)js * NNODES + orow) * 4;
#pragma unroll
    for (int h = 0; h < 4; ++h)
#pragma unroll
      for (int r = 0; r < 4; ++r) dp[r * 4 + h] = accd[h][r];
  }
}

// ---------------------------------------------------------------------------
// Kernel C: sum j-split partials, divide by den, add bias.
// ---------------------------------------------------------------------------
__global__ __launch_bounds__(256) void k_div(
    const float* __restrict__ nump, const float* __restrict__ denp,
    const float* __restrict__ bias, float* __restrict__ out, int sj)
{
  const int q  = blockIdx.x * 256 + threadIdx.x;  // float4 index
  const int n  = q >> 6;
  const int c4 = (q & 63) * 4;
  const int h  = c4 >> 6;
  f32x4 s = {0.f, 0.f, 0.f, 0.f};
  float d = 0.f;
  for (int t = 0; t < sj; ++t) {
    s += *(const f32x4*)(nump + ((size_t)t * NNODES + n) * OUTF + c4);
    d += denp[((size_t)t * NNODES + n) * 4 + h];
  }
  f32x4 b = *(const f32x4*)(bias + c4);
  float r = __builtin_amdgcn_rcpf(d);
  f32x4 o = s * r + b;
  *(f32x4*)(out + (size_t)n * OUTF + c4) = o;
}

extern "C" void kernel_launch(void* const* d_in, const int* in_sizes, int n_in,
                              void* d_out, int out_size, void* d_ws, size_t ws_size,
                              hipStream_t stream)
{
  const float* x    = (const float*)d_in[0];
  const int*   adj  = (const int*)d_in[1];
  const float* W    = (const float*)d_in[2];
  const float* attl = (const float*)d_in[3];
  const float* attr = (const float*)d_in[4];
  const float* bias = (const float*)d_in[5];
  float* out = (float*)d_out;
  char*  ws  = (char*)d_ws;

  // workspace layout
  unsigned short* hT  = (unsigned short*)ws;                        // 2 MB
  float*    el_t  = (float*)(ws + (2u << 20));                      // 64 KB
  u32*      QS    = (u32*)(ws + (2u << 20) + (64u << 10));          // 64 KB
  unsigned* M_enc = (unsigned*)(ws + (2u << 20) + (128u << 10));    // 16 B
  float*    denp  = (float*)(ws + (2u << 20) + (192u << 10));       // <=512 KB
  const size_t nbase = (3u << 20);

  const size_t per_split = (size_t)NNODES * OUTF * 4;
  int sj = 8;
  while (sj > 1 && ws_size < nbase + (size_t)sj * per_split) sj >>= 1;
  float* nump = (sj == 1) ? out : (float*)(ws + nbase);

  hipMemsetAsync(M_enc, 0, 16, stream);
  k_feat<<<dim3(4, 64), 256, 0, stream>>>(x, W, attl, attr, hT, el_t, QS, M_enc);
  k_gat<<<dim3(64, sj), 256, 0, stream>>>(adj, hT, el_t, QS, M_enc, nump, denp, NNODES / sj);
  k_div<<<dim3(1024), 256, 0, stream>>>(nump, denp, bias, out, sj);
}

// Round 4
// 74.095 us; speedup vs baseline: 1.8314x; 1.0611x over previous
//
#include <hip/hip_runtime.h>
#include <hip/hip_bf16.h>
#include <stdint.h>

typedef float f32x4 __attribute__((ext_vector_type(4)));
typedef short s16x8 __attribute__((ext_vector_type(8)));
typedef int   i32x4 __attribute__((ext_vector_type(4)));
typedef unsigned int u32;

#define NNODES 4096
#define INC    256
#define OUTF   256
#define NEG    0.2f

__device__ __forceinline__ unsigned short f2bf(float f) {
  unsigned u = __float_as_uint(f);
  u += 0x7FFFu + ((u >> 16) & 1u);          // RNE
  return (unsigned short)(u >> 16);
}
__device__ __forceinline__ unsigned encf(float x) {
  unsigned u = __float_as_uint(x);
  return (u & 0x80000000u) ? ~u : (u | 0x80000000u);
}
__device__ __forceinline__ float decf(unsigned e) {
  unsigned u = (e & 0x80000000u) ? (e ^ 0x80000000u) : ~e;
  return __uint_as_float(u);
}

// ---------------------------------------------------------------------------
// Kernel A: h = x @ W (f32), write hT (bf16, [c][n], granule-swizzled within
// each 32-n block: granule g of row c stored at g ^ ((c&3)^((c>>2)&3))),
// el logits (f32), QS = packed (bf16 exp(0.2*er) << 16 | bf16 exp(er)),
// atomicMax of global er max per head.
// ---------------------------------------------------------------------------
__global__ __launch_bounds__(256) void k_feat(
    const float* __restrict__ x, const float* __restrict__ W,
    const float* __restrict__ attl, const float* __restrict__ attr,
    unsigned short* __restrict__ hT, float* __restrict__ el_t,
    u32* __restrict__ QS, unsigned* __restrict__ M_enc)
{
  __shared__ float sm[4352];
  float* xs  = sm;          // [32][68]
  float* wsl = sm + 2176;   // [32][68]
  const int tid = threadIdx.x;
  const int hb = blockIdx.x, nb = blockIdx.y;
  const int n0 = nb * 64, c0 = hb * 64;
  const int ty = tid >> 4, tx = tid & 15;

  float acc[4][4];
#pragma unroll
  for (int r = 0; r < 4; ++r)
#pragma unroll
    for (int j = 0; j < 4; ++j) acc[r][j] = 0.f;

  const int sn = tid >> 2, sko = (tid & 3) * 8;
  const int wk = tid >> 3, wco = (tid & 7) * 8;

  for (int kc = 0; kc < INC; kc += 32) {
    __syncthreads();
    {
      const float* xp = x + (size_t)(n0 + sn) * INC + kc + sko;
      float4 a = *(const float4*)xp;
      float4 b = *(const float4*)(xp + 4);
      xs[(sko + 0) * 68 + sn] = a.x; xs[(sko + 1) * 68 + sn] = a.y;
      xs[(sko + 2) * 68 + sn] = a.z; xs[(sko + 3) * 68 + sn] = a.w;
      xs[(sko + 4) * 68 + sn] = b.x; xs[(sko + 5) * 68 + sn] = b.y;
      xs[(sko + 6) * 68 + sn] = b.z; xs[(sko + 7) * 68 + sn] = b.w;
      const float* wp = W + (size_t)(kc + wk) * OUTF + c0 + wco;
      *(float4*)(wsl + wk * 68 + wco)     = *(const float4*)wp;
      *(float4*)(wsl + wk * 68 + wco + 4) = *(const float4*)(wp + 4);
    }
    __syncthreads();
#pragma unroll
    for (int k = 0; k < 32; ++k) {
      float4 a = *(const float4*)(xs + k * 68 + ty * 4);
      float4 b = *(const float4*)(wsl + k * 68 + tx * 4);
      acc[0][0] = fmaf(a.x, b.x, acc[0][0]); acc[0][1] = fmaf(a.x, b.y, acc[0][1]);
      acc[0][2] = fmaf(a.x, b.z, acc[0][2]); acc[0][3] = fmaf(a.x, b.w, acc[0][3]);
      acc[1][0] = fmaf(a.y, b.x, acc[1][0]); acc[1][1] = fmaf(a.y, b.y, acc[1][1]);
      acc[1][2] = fmaf(a.y, b.z, acc[1][2]); acc[1][3] = fmaf(a.y, b.w, acc[1][3]);
      acc[2][0] = fmaf(a.z, b.x, acc[2][0]); acc[2][1] = fmaf(a.z, b.y, acc[2][1]);
      acc[2][2] = fmaf(a.z, b.z, acc[2][2]); acc[2][3] = fmaf(a.z, b.w, acc[2][3]);
      acc[3][0] = fmaf(a.w, b.x, acc[3][0]); acc[3][1] = fmaf(a.w, b.y, acc[3][1]);
      acc[3][2] = fmaf(a.w, b.z, acc[3][2]); acc[3][3] = fmaf(a.w, b.w, acc[3][3]);
    }
  }

  float4 al = *(const float4*)(attl + c0 + tx * 4);
  float4 ar = *(const float4*)(attr + c0 + tx * 4);
  float pl[4], pr[4];
#pragma unroll
  for (int r = 0; r < 4; ++r) {
    pl[r] = acc[r][0] * al.x + acc[r][1] * al.y + acc[r][2] * al.z + acc[r][3] * al.w;
    pr[r] = acc[r][0] * ar.x + acc[r][1] * ar.y + acc[r][2] * ar.z + acc[r][3] * ar.w;
  }
#pragma unroll
  for (int m = 1; m < 16; m <<= 1) {
#pragma unroll
    for (int r = 0; r < 4; ++r) {
      pl[r] += __shfl_xor(pl[r], m, 64);
      pr[r] += __shfl_xor(pr[r], m, 64);
    }
  }
  if (tx == 0) {
#pragma unroll
    for (int r = 0; r < 4; ++r) {
      el_t[hb * NNODES + n0 + ty * 4 + r] = pl[r];
      float q = __expf(pr[r]);
      float s = __expf(NEG * pr[r]);
      QS[hb * NNODES + n0 + ty * 4 + r] = (u32)f2bf(q) | ((u32)f2bf(s) << 16);
    }
  }
  float mx = fmaxf(fmaxf(pr[0], pr[1]), fmaxf(pr[2], pr[3]));
  mx = fmaxf(mx, __shfl_xor(mx, 16, 64));
  mx = fmaxf(mx, __shfl_xor(mx, 32, 64));
  if ((tid & 63) == 0) atomicMax(M_enc + hb, encf(mx));

  __syncthreads();
#pragma unroll
  for (int r = 0; r < 4; ++r)
#pragma unroll
    for (int j = 0; j < 4; ++j)
      sm[(tx * 4 + j) * 68 + ty * 4 + r] = acc[r][j];
  __syncthreads();
  {
    const int c = tid >> 2, ns = (tid & 3) * 16;
    unsigned v[8];
#pragma unroll
    for (int i = 0; i < 8; ++i) {
      unsigned lo = f2bf(sm[c * 68 + ns + 2 * i]);
      unsigned hi = f2bf(sm[c * 68 + ns + 2 * i + 1]);
      v[i] = lo | (hi << 16);
    }
    const int sw = (c & 3) ^ ((c >> 2) & 3);
    const int blk = n0 + (ns & 32);
    const int g0 = (ns & 16) >> 3;          // 0 or 2
    unsigned short* dstb = hT + (size_t)(c0 + c) * NNODES + blk;
    *(uint4*)(dstb + ((g0 ^ sw) * 8))       = make_uint4(v[0], v[1], v[2], v[3]);
    *(uint4*)(dstb + (((g0 + 1) ^ sw) * 8)) = make_uint4(v[4], v[5], v[6], v[7]);
  }
}

// ---------------------------------------------------------------------------
// Kernel B: fused masked-softmax + PV. One wave = 16 i-rows x ALL 4 heads.
// 4-buffer LDS ring for hT (+QS), filled 2 iterations ahead with
// global_load_lds; counted s_waitcnt vmcnt(14) retires exactly iter-k's
// fills+adj while leaving 2 iters in flight. adj in rotating registers
// (lane-private). QS read from LDS is broadcast (16 lanes same addr).
// __launch_bounds__(256,2) pins 2 waves/SIMD (8 waves/CU).
// ---------------------------------------------------------------------------
__global__ __launch_bounds__(256, 2) void k_gat(
    const int* __restrict__ adj, const unsigned short* __restrict__ hT,
    const float* __restrict__ el_t, const u32* __restrict__ QS,
    const unsigned* __restrict__ M_enc,
    float* __restrict__ nump, float* __restrict__ denp, int jlen)
{
  __shared__ __align__(16) unsigned short hbuf[4][8192];   // 4 x 16KB [256 c][32 j]
  __shared__ __align__(16) u32 qbuf[4][128];               // 4 x 512B [4 h][32 j]
  const int tid = threadIdx.x;
  const int wid = tid >> 6, lane = tid & 63;
  const int l15 = lane & 15, lg = lane >> 4;
  const int i0 = (blockIdx.x * 4 + wid) * 16;
  const int js = blockIdx.y;
  const int j0 = js * jlen;
  const int irow = i0 + l15;
  const int sw_l = (l15 & 3) ^ ((l15 >> 2) & 3);

  float P[4], Rr[4];
#pragma unroll
  for (int h = 0; h < 4; ++h) {
    float el  = el_t[h * NNODES + irow];
    float M   = decf(M_enc[h]);
    float sE  = el + M;
    float mih = fmaxf(sE, NEG * sE);
    P[h]  = __expf(el - mih);
    Rr[h] = __expf(NEG * el - mih);
  }

  // fill sources (per-lane global addresses; LDS dests are linear)
  const unsigned short* hsrc = hT + (size_t)(wid * 64 + (lane >> 2)) * NNODES + j0 + (lane & 3) * 8;
  const u32*            qsrc = QS + (size_t)(lane >> 5) * NNODES + j0 + (lane & 31);
  const int*            asrc = adj + (size_t)irow * NNODES + j0 + lg * 8;

  f32x4 acc[4][4];
  f32x4 accd[4];
#pragma unroll
  for (int h = 0; h < 4; ++h) {
    accd[h] = (f32x4){0.f, 0.f, 0.f, 0.f};
#pragma unroll
    for (int c = 0; c < 4; ++c) acc[h][c] = (f32x4){0.f, 0.f, 0.f, 0.f};
  }
  s16x8 ones;
#pragma unroll
  for (int e = 0; e < 8; ++e) ones[e] = (short)0x3F80;  // bf16 1.0

  const int niter = jlen >> 5;

  // 6 fills per iteration (uniform across waves -> uniform vmcnt math)
#define FILL(T, SLOT)                                                            \
  do {                                                                           \
    const unsigned short* hs_ = hsrc + (size_t)(T) * 32;                         \
    _Pragma("unroll")                                                            \
    for (int q_ = 0; q_ < 4; ++q_)                                               \
      __builtin_amdgcn_global_load_lds(hs_ + (size_t)q_ * 16 * NNODES,           \
                                       &hbuf[SLOT][wid * 2048 + q_ * 512], 16, 0, 0); \
    const u32* qs_ = qsrc + (size_t)(T) * 32;                                    \
    __builtin_amdgcn_global_load_lds(qs_,              &qbuf[SLOT][0],  4, 0, 0);\
    __builtin_amdgcn_global_load_lds(qs_ + 2 * NNODES, &qbuf[SLOT][64], 4, 0, 0);\
  } while (0)

  // prologue: issue order matches steady state [f][a][f][a]
  FILL(0, 0);
  i32x4 ac0 = *(const i32x4*)(asrc);
  i32x4 ac1 = *(const i32x4*)(asrc + 4);
  const int t1 = (niter > 1) ? 1 : 0;
  FILL(t1, 1);
  i32x4 an0 = *(const i32x4*)(asrc + (size_t)t1 * 32);
  i32x4 an1 = *(const i32x4*)(asrc + (size_t)t1 * 32 + 4);

  for (int k = 0; k < niter; ++k) {
    const int t2 = (k + 2 < niter) ? (k + 2) : (niter - 1);
    FILL(t2, (k + 2) & 3);
    // retire everything older than the newest 14 VMEM ops
    // (= fills(k+1):6 + adj(k+1):2 + fills(k+2):6) -> fill(k), adj(k) done.
    asm volatile("s_waitcnt vmcnt(14)" ::: "memory");
    const int* ap = asrc + (size_t)t2 * 32;
    i32x4 af0 = *(const i32x4*)(ap);
    i32x4 af1 = *(const i32x4*)(ap + 4);
    __builtin_amdgcn_s_barrier();

    const int cs = k & 3;
#pragma unroll
    for (int h = 0; h < 4; ++h) {
      const unsigned short* lb = &hbuf[cs][(h * 64 + l15) * 32 + ((lg ^ sw_l) * 8)];
      s16x8 b0 = *(const s16x8*)(lb);
      s16x8 b1 = *(const s16x8*)(lb + 16 * 32);
      s16x8 b2 = *(const s16x8*)(lb + 32 * 32);
      s16x8 b3 = *(const s16x8*)(lb + 48 * 32);
      const u32* qrow = &qbuf[cs][h * 32 + lg * 8];
      i32x4 q0 = *(const i32x4*)(qrow);
      i32x4 q1 = *(const i32x4*)(qrow + 4);

      float w[8];
#pragma unroll
      for (int e = 0; e < 4; ++e) {
        u32 m0 = (ac0[e] > 0) ? (u32)q0[e] : 0u;
        u32 m1 = (ac1[e] > 0) ? (u32)q1[e] : 0u;
        float qq0 = __uint_as_float(m0 << 16);
        float ss0 = __uint_as_float(m0 & 0xffff0000u);
        float qq1 = __uint_as_float(m1 << 16);
        float ss1 = __uint_as_float(m1 & 0xffff0000u);
        w[e]     = fmaxf(P[h] * qq0, Rr[h] * ss0);
        w[e + 4] = fmaxf(P[h] * qq1, Rr[h] * ss1);
      }
      union { u32 uu[4]; s16x8 v; } af;
#pragma unroll
      for (int p = 0; p < 4; ++p)
        asm("v_cvt_pk_bf16_f32 %0, %1, %2" : "=v"(af.uu[p]) : "v"(w[2 * p]), "v"(w[2 * p + 1]));

      acc[h][0] = __builtin_amdgcn_mfma_f32_16x16x32_bf16(af.v, b0,   acc[h][0], 0, 0, 0);
      acc[h][1] = __builtin_amdgcn_mfma_f32_16x16x32_bf16(af.v, b1,   acc[h][1], 0, 0, 0);
      acc[h][2] = __builtin_amdgcn_mfma_f32_16x16x32_bf16(af.v, b2,   acc[h][2], 0, 0, 0);
      acc[h][3] = __builtin_amdgcn_mfma_f32_16x16x32_bf16(af.v, b3,   acc[h][3], 0, 0, 0);
      accd[h]   = __builtin_amdgcn_mfma_f32_16x16x32_bf16(af.v, ones, accd[h],   0, 0, 0);
    }

    ac0 = an0; ac1 = an1; an0 = af0; an1 = af1;
  }
#undef FILL

  // C/D layout: col = lane&15, row = (lane>>4)*4 + reg
  const int orow = i0 + lg * 4;
  float* np = nump + ((size_t)js * NNODES + orow) * OUTF + l15;
#pragma unroll
  for (int h = 0; h < 4; ++h)
#pragma unroll
    for (int c = 0; c < 4; ++c)
#pragma unroll
      for (int r = 0; r < 4; ++r)
        np[r * OUTF + h * 64 + c * 16] = acc[h][c][r];

  if (l15 == 0) {
    float* dp = denp + ((size_t)js * NNODES + orow) * 4;
#pragma unroll
    for (int h = 0; h < 4; ++h)
#pragma unroll
      for (int r = 0; r < 4; ++r) dp[r * 4 + h] = accd[h][r];
  }
}

// ---------------------------------------------------------------------------
// Kernel C: sum j-split partials, divide by den, add bias.
// ---------------------------------------------------------------------------
__global__ __launch_bounds__(256) void k_div(
    const float* __restrict__ nump, const float* __restrict__ denp,
    const float* __restrict__ bias, float* __restrict__ out, int sj)
{
  const int q  = blockIdx.x * 256 + threadIdx.x;  // float4 index
  const int n  = q >> 6;
  const int c4 = (q & 63) * 4;
  const int h  = c4 >> 6;
  f32x4 s = {0.f, 0.f, 0.f, 0.f};
  float d = 0.f;
  for (int t = 0; t < sj; ++t) {
    s += *(const f32x4*)(nump + ((size_t)t * NNODES + n) * OUTF + c4);
    d += denp[((size_t)t * NNODES + n) * 4 + h];
  }
  f32x4 b = *(const f32x4*)(bias + c4);
  float r = __builtin_amdgcn_rcpf(d);
  f32x4 o = s * r + b;
  *(f32x4*)(out + (size_t)n * OUTF + c4) = o;
}

extern "C" void kernel_launch(void* const* d_in, const int* in_sizes, int n_in,
                              void* d_out, int out_size, void* d_ws, size_t ws_size,
                              hipStream_t stream)
{
  const float* x    = (const float*)d_in[0];
  const int*   adj  = (const int*)d_in[1];
  const float* W    = (const float*)d_in[2];
  const float* attl = (const float*)d_in[3];
  const float* attr = (const float*)d_in[4];
  const float* bias = (const float*)d_in[5];
  float* out = (float*)d_out;
  char*  ws  = (char*)d_ws;

  // workspace layout
  unsigned short* hT  = (unsigned short*)ws;                        // 2 MB
  float*    el_t  = (float*)(ws + (2u << 20));                      // 64 KB
  u32*      QS    = (u32*)(ws + (2u << 20) + (64u << 10));          // 64 KB
  unsigned* M_enc = (unsigned*)(ws + (2u << 20) + (128u << 10));    // 16 B
  float*    denp  = (float*)(ws + (2u << 20) + (192u << 10));       // <=512 KB
  const size_t nbase = (3u << 20);

  const size_t per_split = (size_t)NNODES * OUTF * 4;
  int sj = 8;
  while (sj > 1 && ws_size < nbase + (size_t)sj * per_split) sj >>= 1;
  float* nump = (sj == 1) ? out : (float*)(ws + nbase);

  hipMemsetAsync(M_enc, 0, 16, stream);
  k_feat<<<dim3(4, 64), 256, 0, stream>>>(x, W, attl, attr, hT, el_t, QS, M_enc);
  k_gat<<<dim3(64, sj), 256, 0, stream>>>(adj, hT, el_t, QS, M_enc, nump, denp, NNODES / sj);
  k_div<<<dim3(1024), 256, 0, stream>>>(nump, denp, bias, out, sj);
}